// Round 3
// baseline (210.186 us; speedup 1.0000x reference)
//
#include <hip/hip_runtime.h>

#define GRID_N 112
#define O_MAX 48
#define HW_N (GRID_N * GRID_N)   // 12544
#define NT 448                   // 7 waves; wave w owns row strip th=w
#define LSTR 72                  // eyT row stride in f16 (144 B rows)

typedef _Float16 half8  __attribute__((ext_vector_type(8)));
typedef _Float16 half2v __attribute__((ext_vector_type(2)));
typedef float    f32x4  __attribute__((ext_vector_type(4)));

// channel[b,h,w] = 0.5 + sum_k A[h,k]*B[w,k], masked by road_mask.
// A rows carry sign/scale: k<n -> -0.5*obj gauss, k==n -> +0.5*goal gauss, k>n -> 0.
// Structure: A-fragments built in registers (no exT, no obj_s), eyT in LDS with
// ONE raw barrier (lgkmcnt drain only -- mask loads stay in flight across it),
// mask loads software-pipelined through the tw sweep so the read stream
// overlaps MFMA + the write stream instead of forming a front-loaded burst.
__global__ __launch_bounds__(NT) void goalmap_kernel(
    const float* __restrict__ xL, const float* __restrict__ yL,
    const float* __restrict__ obj_list, const int* __restrict__ obj_num,
    const int* __restrict__ road_mask, float* __restrict__ out)
{
    constexpr float INV = 1.0f / (2.0f * 5.0f * 5.0f);  // SIGMA = 5.0

    __shared__ _Float16 eyT[GRID_N * LSTR];     // 16128 B (only LDS user)

    const int b   = blockIdx.x;
    const int tid = threadIdx.x;
    const int n   = obj_num[b];                 // uniform -> s_load (lgkmcnt)
    const float xl = xL[b];
    const float yl = yL[b];
    const float* ob = obj_list + (size_t)b * O_MAX * 2;

    const int lane = tid & 63;
    const int wid  = tid >> 6;                  // 0..6, one strip each
    const int m    = lane & 15;
    const int quad = lane >> 4;

    const int* rm = road_mask + (size_t)b * HW_N;
    float*     op = out       + (size_t)b * HW_N;

    const int ksteps = (n >= 32) ? 2 : 1;       // uniform

    // ---- (1) obj-coordinate loads FIRST in the vmcnt queue (consumed early;
    //      FIFO vmcnt means waiting on these never drains the mask loads).
    // eyT-build y-coords: item i = tid + it*NT covers (pos = i>>5, o0 = (i&31)*2)
    float eyy0[8], eyy1[8];
    #pragma unroll
    for (int it = 0; it < 8; ++it) {
        int i  = tid + it * NT;
        int o0 = (i & 31) * 2;
        eyy0[it] = (o0     < n) ? ob[o0 * 2]     : 0.f;  // y of obj o0
        eyy1[it] = (o0 + 1 < n) ? ob[o0 * 2 + 2] : 0.f;  // y of obj o0+1
    }
    // A-frag x-coords for this lane's k-slice
    float ax0[8], ax1[8];
    #pragma unroll
    for (int j = 0; j < 8; ++j) {
        int k = quad * 8 + j;
        ax0[j] = (k < n)      ? ob[k * 2 + 1]        : 0.f;
        ax1[j] = (k + 32 < n) ? ob[(k + 32) * 2 + 1] : 0.f;
    }

    // ---- (2) issue mask loads for the first 3 tiles (pipeline prologue)
    int mpf[7][4];
    const int base_h = wid * 16 + quad * 4;
    #pragma unroll
    for (int twp = 0; twp < 3; ++twp) {
        int base = base_h * GRID_N + twp * 16 + m;
        #pragma unroll
        for (int r = 0; r < 4; ++r)
            mpf[twp][r] = rm[base + r * GRID_N];
    }

    // ---- (3) build eyT [w][k], full KPAD=64 (zeros past n are free: no exp)
    #pragma unroll
    for (int it = 0; it < 8; ++it) {
        int i   = tid + it * NT;
        int pos = i >> 5;
        int o0  = (i & 31) * 2;
        float fp = (float)pos;
        half2v v;
        {   // j = 0
            float val = 0.f;
            if (o0 <= n) {
                float cy = (o0 < n) ? eyy0[it] : yl;
                float d  = fp - cy;
                val = __expf(-d * d * INV);
            }
            v[0] = (_Float16)val;
        }
        {   // j = 1
            int o = o0 + 1;
            float val = 0.f;
            if (o <= n) {
                float cy = (o < n) ? eyy1[it] : yl;
                float d  = fp - cy;
                val = __expf(-d * d * INV);
            }
            v[1] = (_Float16)val;
        }
        *(half2v*)&eyT[pos * LSTR + o0] = v;
    }

    // ---- (4) A-fragments in registers (signed/scaled), no LDS round-trip
    const float fh = (float)(wid * 16 + m);
    half8 a0, a1;
    #pragma unroll
    for (int j = 0; j < 8; ++j) {
        int k = quad * 8 + j;
        float val = 0.f;
        if (k <= n) {
            float cx = (k < n) ? ax0[j] : xl;
            float s  = (k < n) ? -0.5f  : 0.5f;
            float d  = fh - cx;
            val = s * __expf(-d * d * INV);
        }
        a0[j] = (_Float16)val;
    }
    if (ksteps == 2) {
        #pragma unroll
        for (int j = 0; j < 8; ++j) {
            int k = quad * 8 + j + 32;
            float val = 0.f;
            if (k <= n) {
                float cx = (k < n) ? ax1[j] : xl;
                float s  = (k < n) ? -0.5f  : 0.5f;
                float d  = fh - cx;
                val = s * __expf(-d * d * INV);
            }
            a1[j] = (_Float16)val;
        }
    }

    // ---- (5) light barrier: drain LDS writes ONLY. Mask loads stay in flight.
    __builtin_amdgcn_sched_barrier(0);
    asm volatile("s_waitcnt lgkmcnt(0)" ::: "memory");
    __builtin_amdgcn_s_barrier();
    __builtin_amdgcn_sched_barrier(0);

    // ---- (6) tw sweep: consume mpf[tw], issue masks for tw+3 (JIT pipeline)
    const int h0 = wid * 16 + quad * 4;
    #pragma unroll
    for (int tw = 0; tw < 7; ++tw) {
        if (tw + 3 < 7) {
            int base = base_h * GRID_N + (tw + 3) * 16 + m;
            #pragma unroll
            for (int r = 0; r < 4; ++r)
                mpf[tw + 3][r] = rm[base + r * GRID_N];
        }
        const _Float16* brow = &eyT[(tw * 16 + m) * LSTR + quad * 8];
        half8 b0 = *(const half8*)brow;
        f32x4 acc = {0.f, 0.f, 0.f, 0.f};
        acc = __builtin_amdgcn_mfma_f32_16x16x32_f16(a0, b0, acc, 0, 0, 0);
        if (ksteps == 2) {
            half8 b1 = *(const half8*)(brow + 32);
            acc = __builtin_amdgcn_mfma_f32_16x16x32_f16(a1, b1, acc, 0, 0, 0);
        }
        int w0 = tw * 16 + m;
        #pragma unroll
        for (int r = 0; r < 4; ++r) {
            float v = 0.5f + acc[r];
            v = (mpf[tw][r] == 0) ? 0.f : v;
            op[(h0 + r) * GRID_N + w0] = v;
        }
    }
}

extern "C" void kernel_launch(void* const* d_in, const int* in_sizes, int n_in,
                              void* d_out, int out_size, void* d_ws, size_t ws_size,
                              hipStream_t stream) {
    const float* xL        = (const float*)d_in[0];
    const float* yL        = (const float*)d_in[1];
    const float* obj_list  = (const float*)d_in[2];
    const int*   obj_num   = (const int*)d_in[3];
    const int*   road_mask = (const int*)d_in[4];
    float*       out       = (float*)d_out;
    const int B = in_sizes[0];  // 2048

    goalmap_kernel<<<B, NT, 0, stream>>>(xL, yL, obj_list, obj_num, road_mask, out);
}

// Round 4
// 203.171 us; speedup vs baseline: 1.0345x; 1.0345x over previous
//
#include <hip/hip_runtime.h>

#define GRID_N 112
#define O_MAX 48
#define HW_N (GRID_N * GRID_N)   // 12544
#define NT 448                   // 7 waves; wave w owns row strip th=w
#define NB 4                     // batches per block (cross-batch read pipeline)
#define LSTR 72                  // eyT row stride in f16 (144 B rows)

typedef _Float16 half8  __attribute__((ext_vector_type(8)));
typedef _Float16 half2v __attribute__((ext_vector_type(2)));
typedef float    f32x4  __attribute__((ext_vector_type(4)));

// channel[b,h,w] = 0.5 + sum_k A[h,k]*B[w,k], masked by road_mask.
// Multi-batch blocks: while batch j computes (build/MFMA/store), batch j+1's
// full mask tile is in flight in registers (mpf double buffer). The per-CU
// outstanding-read queue never empties -> read stream duty cycle ~100%
// (was: front-loaded burst then silence, ~0.8 TB/s read).
__global__ __launch_bounds__(NT) void goalmap_kernel(
    const float* __restrict__ xL, const float* __restrict__ yL,
    const float* __restrict__ obj_list, const int* __restrict__ obj_num,
    const int* __restrict__ road_mask, float* __restrict__ out, int B)
{
    constexpr float INV = 1.0f / (2.0f * 5.0f * 5.0f);  // SIGMA = 5.0

    __shared__ _Float16 eyT[2][GRID_N * LSTR];   // 2 x 16128 B, double-buffered

    const int tid  = threadIdx.x;
    const int lane = tid & 63;
    const int wid  = tid >> 6;                  // 0..6, one row strip each
    const int m    = lane & 15;
    const int quad = lane >> 4;
    const int base_h = wid * 16 + quad * 4;     // this lane's output row base
    const int b0 = blockIdx.x * NB;

    int mpf[2][7][4];                           // mask double buffer (regs)

    // ---- prologue: issue batch-0 mask loads (28 dwords/lane in flight)
    {
        const int* rm = road_mask + (size_t)b0 * HW_N;
        #pragma unroll
        for (int i = 0; i < 7; ++i) {
            int base = base_h * GRID_N + i * 16 + m;
            #pragma unroll
            for (int r = 0; r < 4; ++r)
                mpf[0][i][r] = rm[base + r * GRID_N];
        }
    }
    __builtin_amdgcn_sched_barrier(0);

    // i = tid + it*NT: NT % 32 == 0 -> (i&31) == (tid&31): lane's k-pair is
    // loop-invariant; pos = (tid>>5) + it*14 covers 0..111 exactly once.
    const int o0   = (tid & 31) * 2;
    const int posb = tid >> 5;
    const float fh = (float)(wid * 16 + m);

    #pragma unroll
    for (int j = 0; j < NB; ++j) {
        const int b = b0 + j;
        if (b >= B) break;                      // uniform
        const int cur = j & 1;                  // compile-time after unroll
        _Float16* ey = eyT[cur];

        // scalar batch params (SMEM/lgkm path -- doesn't touch vmcnt)
        const int n  = obj_num[b];
        const float xl = xL[b];
        const float yl = yL[b];
        const float* ob = obj_list + (size_t)b * (O_MAX * 2);

        // ---- obj gathers for batch j, issued BEFORE next-batch masks so
        //      waiting on them (vmcnt FIFO) leaves the mask queue in flight.
        float y0 = (o0     < n) ? ob[o0 * 2]     : 0.f;   // y of obj o0
        float y1 = (o0 + 1 < n) ? ob[o0 * 2 + 2] : 0.f;   // y of obj o0+1
        float ax0[8], ax1[8];
        #pragma unroll
        for (int jj = 0; jj < 8; ++jj) {
            int k = quad * 8 + jj;
            ax0[jj] = ob[k * 2 + 1];                            // k<32: in-bounds
            ax1[jj] = (k + 32 < n) ? ob[k * 2 + 65] : 0.f;      // (k+32)*2+1
        }
        __builtin_amdgcn_sched_barrier(0);

        // ---- issue NEXT batch's mask loads; they stay outstanding through
        //      this batch's entire build+sweep (the whole point).
        if (j + 1 < NB && b + 1 < B) {
            const int* rm = road_mask + (size_t)(b + 1) * HW_N;
            #pragma unroll
            for (int i = 0; i < 7; ++i) {
                int base = base_h * GRID_N + i * 16 + m;
                #pragma unroll
                for (int r = 0; r < 4; ++r)
                    mpf[cur ^ 1][i][r] = rm[base + r * GRID_N];
            }
        }
        __builtin_amdgcn_sched_barrier(0);

        const int ksteps = (n >= 32) ? 2 : 1;   // uniform

        // ---- build eyT[cur]: each lane owns k-pair (o0,o0+1), 8 rows
        #pragma unroll
        for (int it = 0; it < 8; ++it) {
            int pos  = posb + it * 14;
            float fp = (float)pos;
            half2v v;
            {   // k = o0
                float val = 0.f;
                if (o0 <= n) {
                    float cy = (o0 < n) ? y0 : yl;
                    float d  = fp - cy;
                    val = __expf(-d * d * INV);
                }
                v[0] = (_Float16)val;
            }
            {   // k = o0+1
                int o = o0 + 1;
                float val = 0.f;
                if (o <= n) {
                    float cy = (o < n) ? y1 : yl;
                    float d  = fp - cy;
                    val = __expf(-d * d * INV);
                }
                v[1] = (_Float16)val;
            }
            *(half2v*)&ey[pos * LSTR + o0] = v;
        }

        // ---- A-fragments in registers (signed/scaled)
        half8 a0, a1;
        #pragma unroll
        for (int jj = 0; jj < 8; ++jj) {
            int k = quad * 8 + jj;
            float val = 0.f;
            if (k <= n) {
                float cx = (k < n) ? ax0[jj] : xl;
                float s  = (k < n) ? -0.5f  : 0.5f;
                float d  = fh - cx;
                val = s * __expf(-d * d * INV);
            }
            a0[jj] = (_Float16)val;
        }
        if (ksteps == 2) {
            #pragma unroll
            for (int jj = 0; jj < 8; ++jj) {
                int k = quad * 8 + jj + 32;
                float val = 0.f;
                if (k <= n) {
                    float cx = (k < n) ? ax1[jj] : xl;
                    float s  = (k < n) ? -0.5f  : 0.5f;
                    float d  = fh - cx;
                    val = s * __expf(-d * d * INV);
                }
                a1[jj] = (_Float16)val;
            }
        }

        // ---- ONE barrier per batch: LDS drain only, vmcnt untouched.
        //      (Double-buffered eyT: sweep_{j-1} readers of eyT[cur^1] all
        //      passed the previous barrier before build_j wrote eyT[cur].)
        __builtin_amdgcn_sched_barrier(0);
        asm volatile("s_waitcnt lgkmcnt(0)" ::: "memory");
        __builtin_amdgcn_s_barrier();
        __builtin_amdgcn_sched_barrier(0);

        // ---- sweep 7 tiles: MFMA + mask select + stores (overlaps j+1 reads)
        #pragma unroll
        for (int tw = 0; tw < 7; ++tw) {
            const _Float16* brow = &ey[(tw * 16 + m) * LSTR + quad * 8];
            half8 bf0 = *(const half8*)brow;
            f32x4 acc = {0.f, 0.f, 0.f, 0.f};
            acc = __builtin_amdgcn_mfma_f32_16x16x32_f16(a0, bf0, acc, 0, 0, 0);
            if (ksteps == 2) {
                half8 bf1 = *(const half8*)(brow + 32);
                acc = __builtin_amdgcn_mfma_f32_16x16x32_f16(a1, bf1, acc, 0, 0, 0);
            }
            float* op = out + (size_t)b * HW_N;
            int w0 = tw * 16 + m;
            #pragma unroll
            for (int r = 0; r < 4; ++r) {
                float v = 0.5f + acc[r];
                v = (mpf[cur][tw][r] == 0) ? 0.f : v;
                op[(base_h + r) * GRID_N + w0] = v;
            }
        }
    }
}

extern "C" void kernel_launch(void* const* d_in, const int* in_sizes, int n_in,
                              void* d_out, int out_size, void* d_ws, size_t ws_size,
                              hipStream_t stream) {
    const float* xL        = (const float*)d_in[0];
    const float* yL        = (const float*)d_in[1];
    const float* obj_list  = (const float*)d_in[2];
    const int*   obj_num   = (const int*)d_in[3];
    const int*   road_mask = (const int*)d_in[4];
    float*       out       = (float*)d_out;
    const int B = in_sizes[0];  // 2048

    const int grid = (B + NB - 1) / NB;  // 512
    goalmap_kernel<<<grid, NT, 0, stream>>>(xL, yL, obj_list, obj_num, road_mask, out, B);
}